// Round 8
// baseline (330.346 us; speedup 1.0000x reference)
//
#include <hip/hip_runtime.h>

#define N_NODES 50000
#define HIDDEN 128
#define NUM_GRAPHS 64
#define NUM_CLASSES 6
#define SCAN_NB ((N_NODES + 255) / 256)   // 196
#define N_PAD 50048                       // N rounded up to 64
#define DEG_STRIDE 16                     // one counter per 64B line
#define LDS_STRIDE 136                    // 128 + 8 pad (shorts) -> 2-way max bank conflict

typedef __attribute__((ext_vector_type(8))) short short8;
typedef __attribute__((ext_vector_type(4))) float float4v;

__device__ __forceinline__ float b2f(unsigned short u) {
    return __uint_as_float(((unsigned)u) << 16);
}
__device__ __forceinline__ unsigned short f2b(float f) {
    unsigned u = __float_as_uint(f);
    return (unsigned short)((u + 0x7FFFu + ((u >> 16) & 1u)) >> 16);
}

// ---------------- degree + per-edge rank ----------------
__global__ void count_deg(const int* __restrict__ dst, int* __restrict__ deg,
                          int* __restrict__ rank, int e) {
    int i = blockIdx.x * 256 + threadIdx.x;
    if (i < e) rank[i] = atomicAdd(&deg[dst[i] * DEG_STRIDE], 1);
}

// ---------------- scan phase 1: block sums (+ dinv fold) ----------------
__global__ __launch_bounds__(256) void scan_b1(const int* __restrict__ deg, int* partial,
                                               float* __restrict__ dinv, int n) {
    __shared__ int red[4];
    const int t = threadIdx.x;
    const int i = blockIdx.x * 256 + t;
    int dv = (i < n) ? (deg[i * DEG_STRIDE] + 1) : 0;
    if (i < n) dinv[i] = rsqrtf((float)dv);
    int v = dv;
    for (int d = 32; d > 0; d >>= 1) v += __shfl_down(v, d, 64);
    if ((t & 63) == 0) red[t >> 6] = v;
    __syncthreads();
    if (t == 0) partial[blockIdx.x] = red[0] + red[1] + red[2] + red[3];
}

__global__ __launch_bounds__(256) void scan_b2(int* partial, int* off_n, int nb) {
    __shared__ int s[256];
    const int t = threadIdx.x;
    int v = (t < nb) ? partial[t] : 0;
    s[t] = v;
    __syncthreads();
    for (int d = 1; d < 256; d <<= 1) {
        int u = (t >= d) ? s[t - d] : 0;
        __syncthreads();
        s[t] += u;
        __syncthreads();
    }
    if (t < nb) partial[t] = s[t];
    if (t == nb - 1) *off_n = s[t];
}

// ---------------- scan phase 3 (+ self-entry fold) ----------------
__global__ __launch_bounds__(256) void scan_b3(const int* __restrict__ deg, const int* __restrict__ partial,
                                               int* off, int* __restrict__ csr_col, int n) {
    __shared__ int s[256];
    const int t = threadIdx.x;
    const int b = blockIdx.x;
    const int i = b * 256 + t;
    int v = (i < n) ? (deg[i * DEG_STRIDE] + 1) : 0;
    s[t] = v;
    __syncthreads();
    for (int d = 1; d < 256; d <<= 1) {
        int u = (t >= d) ? s[t - d] : 0;
        __syncthreads();
        s[t] += u;
        __syncthreads();
    }
    int base = (b == 0) ? 0 : partial[b - 1];
    if (i < n) {
        int pos = base + s[t] - v;       // exclusive scan
        off[i] = pos;
        csr_col[pos] = i;                // self-loop first in segment
    }
}

// ---------------- CSR fill (edges), atomic-free ----------------
__global__ void fill_edge(const int* __restrict__ src, const int* __restrict__ dst,
                          const int* __restrict__ rank, const int* __restrict__ off,
                          int* __restrict__ csr_col, int e) {
    int i = blockIdx.x * 256 + threadIdx.x;
    if (i >= e) return;
    int d = dst[i];
    int pos = off[d] + 1 + rank[i];
    csr_col[pos] = src[i];
}

// ---------------- cast x f32 -> bf16, pre-scaled by dinv[row] ----------------
__global__ void cast_x(const float* __restrict__ x, const float* __restrict__ dinv,
                       unsigned short* __restrict__ xs, int total) {
    int i = (blockIdx.x * 256 + threadIdx.x) * 4;
    if (i >= total) return;
    float sc = dinv[i >> 7];
    float4 v = *(const float4*)&x[i];
    ushort4 o;
    o.x = f2b(v.x * sc); o.y = f2b(v.y * sc); o.z = f2b(v.z * sc); o.w = f2b(v.w * sc);
    *(ushort4*)&xs[i] = o;
}

// ---------------- convert W0/W1/W2 into MFMA-B fragment order, bf16 ----------------
__global__ void conv_w(const float* __restrict__ W0, const float* __restrict__ W1,
                       const float* __restrict__ W2, unsigned short* __restrict__ wb) {
    int i = blockIdx.x * 256 + threadIdx.x;
    if (i >= 3 * 16384) return;
    int wsel = i >> 14;
    int r = i & 16383;
    int j = r & 7;
    int lane = (r >> 3) & 63;
    int f = r >> 9;               // 0..31
    int ki = f >> 3, nt = f & 7;
    int k = ki * 32 + (lane >> 4) * 8 + j;
    int c = nt * 16 + (lane & 15);
    const float* W = (wsel == 0) ? W0 : ((wsel == 1) ? W1 : W2);
    wb[i] = f2b(W[k * 128 + c]);
}

// ---------------- fused layer: h_out = [rowscale*] relu((dinv .* (A @ hs)) @ W + b) ----------------
// Block = 64 nodes. Phase 1: each wave aggregates 16 nodes -> bf16 t rows in LDS.
// Phase 2: each wave MFMAs its 16x128 tile, A from LDS, B (weights) from global (L2-hot).
__global__ __launch_bounds__(256) void agg_gemm(const unsigned short* __restrict__ hs,
                                                const int* __restrict__ off,
                                                const int* __restrict__ csr_col,
                                                const float* __restrict__ dinv,
                                                const unsigned short* __restrict__ wb,
                                                const float* __restrict__ bias,
                                                const float* __restrict__ rowscale,
                                                unsigned short* __restrict__ hout, int n) {
    __shared__ unsigned short lds[64 * LDS_STRIDE];
    const int lane = threadIdx.x & 63;
    const int wave = threadIdx.x >> 6;
    const int grp = lane >> 4;      // 0..3
    const int fl = lane & 15;       // feature sub-lane
    const int r0 = blockIdx.x * 64;

    // ---- phase 1: aggregate 16 nodes per wave ----
    for (int i = 0; i < 16; i++) {
        const int node = r0 + wave * 16 + i;
        float acc[8];
#pragma unroll
        for (int j = 0; j < 8; j++) acc[j] = 0.f;
        if (node < n) {
            const int p0 = off[node], p1 = off[node + 1];
            for (int base = p0; base < p1; base += 64) {
                const int nb = min(64, p1 - base);
                const int nbm1 = nb - 1;
                int myc = (lane < nb) ? csr_col[base + lane] : 0;
                for (int c0 = 0; c0 < nb; c0 += 16) {
                    int cc[4];
                    float m4[4];
#pragma unroll
                    for (int k = 0; k < 4; k++) {
                        int e = c0 + k * 4 + grp;
                        m4[k] = (e < nb) ? 1.f : 0.f;
                        cc[k] = __shfl(myc, min(e, nbm1), 64);
                    }
                    short8 u[4];
#pragma unroll
                    for (int k = 0; k < 4; k++)
                        u[k] = *(const short8*)&hs[cc[k] * 128 + fl * 8];
#pragma unroll
                    for (int k = 0; k < 4; k++)
#pragma unroll
                        for (int j = 0; j < 8; j++)
                            acc[j] += m4[k] * b2f((unsigned short)u[k][j]);
                }
            }
        }
#pragma unroll
        for (int j = 0; j < 8; j++) {
            acc[j] += __shfl_xor(acc[j], 16, 64);
            acc[j] += __shfl_xor(acc[j], 32, 64);
        }
        if (grp == 0) {
            const float dv = (node < n) ? dinv[node] : 0.f;
            short8 o;
#pragma unroll
            for (int j = 0; j < 8; j++) o[j] = (short)f2b(acc[j] * dv);
            *(short8*)&lds[(wave * 16 + i) * LDS_STRIDE + fl * 8] = o;
        }
    }
    __syncthreads();

    // ---- phase 2: 16x128 MFMA tile per wave, A from LDS ----
    const int m = fl;
    const int quad = grp;
    const short* B = (const short*)wb;
    float4v acc2[8];
#pragma unroll
    for (int nt = 0; nt < 8; nt++) acc2[nt] = (float4v){0.f, 0.f, 0.f, 0.f};

#pragma unroll
    for (int ki = 0; ki < 4; ki++) {
        short8 a = *(const short8*)&lds[(wave * 16 + m) * LDS_STRIDE + ki * 32 + quad * 8];
#pragma unroll
        for (int nt = 0; nt < 8; nt++) {
            short8 b = *(const short8*)&B[((ki * 8 + nt) * 64 + lane) * 8];
            acc2[nt] = __builtin_amdgcn_mfma_f32_16x16x32_bf16(a, b, acc2[nt], 0, 0, 0);
        }
    }

    const int rbase = r0 + wave * 16;
    float sc[4];
#pragma unroll
    for (int reg = 0; reg < 4; reg++) {
        int row = rbase + quad * 4 + reg;
        sc[reg] = (rowscale && row < n) ? rowscale[row] : 1.f;
    }

#pragma unroll
    for (int nt = 0; nt < 8; nt++) {
        int c = nt * 16 + m;
        float bv = bias[c];
#pragma unroll
        for (int reg = 0; reg < 4; reg++) {
            int row = rbase + quad * 4 + reg;
            if (row < n) {
                float v = fmaxf(acc2[nt][reg] + bv, 0.f) * sc[reg];
                hout[row * 128 + c] = f2b(v);
            }
        }
    }
}

// ---------------- pooling (batch sorted), bf16 input ----------------
__global__ __launch_bounds__(128) void pool_kernel(const unsigned short* __restrict__ h, const int* __restrict__ batch,
                                                   float* emb, int* cnt, int n) {
    const int f = threadIdx.x;        // 0..127
    const int n0 = blockIdx.x * 64;
    const int n1 = min(n0 + 64, n);
    float s = 0.f;
    int cloc = 0;
    int curg = batch[n0];
    for (int nn = n0; nn < n1; nn++) {
        int g = batch[nn];
        if (g != curg) {
            atomicAdd(&emb[curg * HIDDEN + f], s);
            if (f == 0) atomicAdd(&cnt[curg], cloc);
            s = 0.f;
            cloc = 0;
            curg = g;
        }
        s += b2f(h[nn * HIDDEN + f]);
        cloc++;
    }
    atomicAdd(&emb[curg * HIDDEN + f], s);
    if (f == 0) atomicAdd(&cnt[curg], cloc);
}

// ---------------- finalize ----------------
__global__ __launch_bounds__(128) void finalize_kernel(const float* __restrict__ emb, const int* __restrict__ cnt,
                                                       const float* __restrict__ linW, const float* __restrict__ linb,
                                                       float* out) {
    const int g = blockIdx.x;
    const int f = threadIdx.x;
    __shared__ float es[128];
    float c = (float)max(cnt[g], 1);
    float e = emb[g * HIDDEN + f] / c;
    out[NUM_GRAPHS * NUM_CLASSES + g * HIDDEN + f] = e;
    es[f] = e;
    __syncthreads();
    if (f < NUM_CLASSES) {
        float s = linb[f];
        for (int k = 0; k < HIDDEN; k++) s += es[k] * linW[k * NUM_CLASSES + f];
        out[g * NUM_CLASSES + f] = s;
    }
}

extern "C" void kernel_launch(void* const* d_in, const int* in_sizes, int n_in,
                              void* d_out, int out_size, void* d_ws, size_t ws_size,
                              hipStream_t stream) {
    const float* x    = (const float*)d_in[0];
    const int*   ei   = (const int*)d_in[1];
    const int*   batch= (const int*)d_in[2];
    const float* W0   = (const float*)d_in[3];
    const float* b0   = (const float*)d_in[4];
    const float* W1   = (const float*)d_in[5];
    const float* b1   = (const float*)d_in[6];
    const float* W2   = (const float*)d_in[7];
    const float* b2   = (const float*)d_in[8];
    const float* linW = (const float*)d_in[9];
    const float* linb = (const float*)d_in[10];
    float* out = (float*)d_out;

    const int N = N_NODES;
    const int E = in_sizes[1] / 2;
    const int M = E + N;
    const int* srcp = ei;
    const int* dstp = ei + E;

    char* w = (char*)d_ws;
    size_t o = 0;
    auto alloc = [&](size_t bytes) { size_t r = o; o += (bytes + 255) & ~(size_t)255; return r; };
    int*            off_i   = (int*)           (w + alloc((size_t)(N + 1) * 4));
    int*            deg     = (int*)           (w + alloc((size_t)N * DEG_STRIDE * 4));
    float*          dinv    = (float*)         (w + alloc((size_t)N * 4));
    int*            partial = (int*)           (w + alloc((size_t)SCAN_NB * 4));
    int*            rank    = (int*)           (w + alloc((size_t)E * 4));
    int*            csr_col = (int*)           (w + alloc((size_t)M * 4));
    unsigned short* xs      = (unsigned short*)(w + alloc((size_t)N_PAD * HIDDEN * 2));
    unsigned short* hb      = (unsigned short*)(w + alloc((size_t)N_PAD * HIDDEN * 2));
    unsigned short* hc      = (unsigned short*)(w + alloc((size_t)N_PAD * HIDDEN * 2));
    unsigned short* wb      = (unsigned short*)(w + alloc((size_t)3 * 16384 * 2));
    float*          emb     = (float*)         (w + alloc((size_t)NUM_GRAPHS * HIDDEN * 4));
    int*            cnt     = (int*)           (w + alloc((size_t)NUM_GRAPHS * 4));

    hipMemsetAsync(deg, 0, (size_t)N * DEG_STRIDE * 4, stream);
    hipMemsetAsync(emb, 0, (size_t)(NUM_GRAPHS * HIDDEN * 4 + 256 + NUM_GRAPHS * 4), stream); // emb + pad + cnt

    conv_w<<<(3 * 16384 + 255) / 256, 256, 0, stream>>>(W0, W1, W2, wb);

    count_deg<<<(E + 255) / 256, 256, 0, stream>>>(dstp, deg, rank, E);

    scan_b1<<<SCAN_NB, 256, 0, stream>>>(deg, partial, dinv, N);
    scan_b2<<<1, 256, 0, stream>>>(partial, off_i + N, SCAN_NB);
    scan_b3<<<SCAN_NB, 256, 0, stream>>>(deg, partial, off_i, csr_col, N);

    cast_x<<<(N * HIDDEN / 4 + 255) / 256, 256, 0, stream>>>(x, dinv, xs, N * HIDDEN);
    fill_edge<<<(E + 255) / 256, 256, 0, stream>>>(srcp, dstp, rank, off_i, csr_col, E);

    const int fuse_grid = (N + 63) / 64;   // 782

    agg_gemm<<<fuse_grid, 256, 0, stream>>>(xs, off_i, csr_col, dinv, wb + 0 * 16384, b0, dinv, hb, N);
    agg_gemm<<<fuse_grid, 256, 0, stream>>>(hb, off_i, csr_col, dinv, wb + 1 * 16384, b1, dinv, hc, N);
    agg_gemm<<<fuse_grid, 256, 0, stream>>>(hc, off_i, csr_col, dinv, wb + 2 * 16384, b2, (const float*)nullptr, hb, N);

    pool_kernel<<<(N + 63) / 64, 128, 0, stream>>>(hb, batch, emb, cnt, N);
    finalize_kernel<<<NUM_GRAPHS, 128, 0, stream>>>(emb, cnt, linW, linb, out);
}

// Round 9
// 314.399 us; speedup vs baseline: 1.0507x; 1.0507x over previous
//
#include <hip/hip_runtime.h>

#define N_NODES 50000
#define HIDDEN 128
#define NUM_GRAPHS 64
#define NUM_CLASSES 6
#define SCAN_NB ((N_NODES + 255) / 256)   // 196
#define N_PAD 50048                       // N rounded up to 64
#define DEG_STRIDE 16                     // one counter per 64B line
#define CONV_BLOCKS 192                   // 3*16384/256
#define CASTX_BLOCKS ((N_NODES * HIDDEN / 4) / 256)  // 6250

typedef __attribute__((ext_vector_type(8))) short short8;
typedef __attribute__((ext_vector_type(4))) float float4v;

__device__ __forceinline__ float b2f(unsigned short u) {
    return __uint_as_float(((unsigned)u) << 16);
}
__device__ __forceinline__ unsigned short f2b(float f) {
    unsigned u = __float_as_uint(f);
    return (unsigned short)((u + 0x7FFFu + ((u >> 16) & 1u)) >> 16);
}

// ---------------- prologue: conv_w (blocks [0,192)) + count_deg (rest) ----------------
__global__ __launch_bounds__(256) void prologue(const float* __restrict__ W0, const float* __restrict__ W1,
                                                const float* __restrict__ W2, unsigned short* __restrict__ wb,
                                                const int* __restrict__ dst, int* __restrict__ deg,
                                                int* __restrict__ rank, int e) {
    if (blockIdx.x < CONV_BLOCKS) {
        int i = blockIdx.x * 256 + threadIdx.x;   // < 3*16384 guaranteed
        int wsel = i >> 14;
        int r = i & 16383;
        int j = r & 7;
        int lane = (r >> 3) & 63;
        int f = r >> 9;               // 0..31
        int ki = f >> 3, nt = f & 7;
        int k = ki * 32 + (lane >> 4) * 8 + j;
        int c = nt * 16 + (lane & 15);
        const float* W = (wsel == 0) ? W0 : ((wsel == 1) ? W1 : W2);
        wb[i] = f2b(W[k * 128 + c]);
    } else {
        int i = (blockIdx.x - CONV_BLOCKS) * 256 + threadIdx.x;
        if (i < e) rank[i] = atomicAdd(&deg[dst[i] * DEG_STRIDE], 1);
    }
}

// ---------------- scan phase 1: block sums (+ dinv fold) ----------------
__global__ __launch_bounds__(256) void scan_b1(const int* __restrict__ deg, int* partial,
                                               float* __restrict__ dinv, int n) {
    __shared__ int red[4];
    const int t = threadIdx.x;
    const int i = blockIdx.x * 256 + t;
    int dv = (i < n) ? (deg[i * DEG_STRIDE] + 1) : 0;
    if (i < n) dinv[i] = rsqrtf((float)dv);
    int v = dv;
    for (int d = 32; d > 0; d >>= 1) v += __shfl_down(v, d, 64);
    if ((t & 63) == 0) red[t >> 6] = v;
    __syncthreads();
    if (t == 0) partial[blockIdx.x] = red[0] + red[1] + red[2] + red[3];
}

// ---------------- scan phase 3 (folds scan_b2 + self-entry) ----------------
__global__ __launch_bounds__(256) void scan_b3(const int* __restrict__ deg, const int* __restrict__ partial,
                                               int* off, int* __restrict__ csr_col, int n) {
    __shared__ int s[256];
    __shared__ int ps[256];
    const int t = threadIdx.x;
    const int b = blockIdx.x;
    const int i = b * 256 + t;
    int v = (i < n) ? (deg[i * DEG_STRIDE] + 1) : 0;
    s[t] = v;
    int pv = (t < SCAN_NB) ? partial[t] : 0;
    ps[t] = pv;
    __syncthreads();
    for (int d = 1; d < 256; d <<= 1) {
        int u1 = (t >= d) ? s[t - d] : 0;
        int u2 = (t >= d) ? ps[t - d] : 0;
        __syncthreads();
        s[t] += u1;
        ps[t] += u2;
        __syncthreads();
    }
    int base = (b == 0) ? 0 : ps[b - 1];
    if (i < n) {
        int pos = base + s[t] - v;       // exclusive scan
        off[i] = pos;
        csr_col[pos] = i;                // self-loop first in segment
        if (i == n - 1) off[n] = base + s[t];
    }
}

// ---------------- mid: cast_x (blocks [0,6250)) + fill_edge (rest) ----------------
__global__ __launch_bounds__(256) void midprep(const float* __restrict__ x, const float* __restrict__ dinv,
                                               unsigned short* __restrict__ xs,
                                               const int* __restrict__ src, const int* __restrict__ dst,
                                               const int* __restrict__ rank, const int* __restrict__ off,
                                               int* __restrict__ csr_col, int e) {
    if (blockIdx.x < CASTX_BLOCKS) {
        int i = (blockIdx.x * 256 + threadIdx.x) * 4;   // < N*128 guaranteed
        float sc = dinv[i >> 7];
        float4 v = *(const float4*)&x[i];
        ushort4 o;
        o.x = f2b(v.x * sc); o.y = f2b(v.y * sc); o.z = f2b(v.z * sc); o.w = f2b(v.w * sc);
        *(ushort4*)&xs[i] = o;
    } else {
        int i = (blockIdx.x - CASTX_BLOCKS) * 256 + threadIdx.x;
        if (i >= e) return;
        int d = dst[i];
        int pos = off[d] + 1 + rank[i];
        csr_col[pos] = src[i];
    }
}

// ---------------- aggregation: t[d] = dinv[d] * sum_p hs[col[p]] ----------------
// wave/node; 4 lane-groups; 32 edges per inner iter = 8 independent gathers in flight per lane
__global__ __launch_bounds__(256) void agg_bf16(const unsigned short* __restrict__ hs, const int* __restrict__ off,
                                                const int* __restrict__ csr_col, const float* __restrict__ dinv,
                                                unsigned short* __restrict__ tb, int n) {
    const int wave = threadIdx.x >> 6;
    const int lane = threadIdx.x & 63;
    const int node = blockIdx.x * 4 + wave;
    if (node >= n) return;
    const int p0 = off[node], p1 = off[node + 1];
    const int grp = lane >> 4;      // 0..3: edge-in-chunk group
    const int fl = lane & 15;       // features fl*8 .. fl*8+7

    float acc[8];
#pragma unroll
    for (int j = 0; j < 8; j++) acc[j] = 0.f;

    for (int base = p0; base < p1; base += 64) {
        const int nb = min(64, p1 - base);
        const int nbm1 = nb - 1;
        int myc = (lane < nb) ? csr_col[base + lane] : 0;
        for (int c0 = 0; c0 < nb; c0 += 32) {
            int cc[8];
            float m[8];
#pragma unroll
            for (int k = 0; k < 8; k++) {
                int e = c0 + k * 4 + grp;
                m[k] = (e < nb) ? 1.f : 0.f;
                cc[k] = __shfl(myc, min(e, nbm1), 64);
            }
            short8 u[8];
#pragma unroll
            for (int k = 0; k < 8; k++)
                u[k] = *(const short8*)&hs[cc[k] * 128 + fl * 8];
#pragma unroll
            for (int k = 0; k < 8; k++)
#pragma unroll
                for (int j = 0; j < 8; j++)
                    acc[j] += m[k] * b2f((unsigned short)u[k][j]);
        }
    }

#pragma unroll
    for (int j = 0; j < 8; j++) {
        acc[j] += __shfl_xor(acc[j], 16, 64);
        acc[j] += __shfl_xor(acc[j], 32, 64);
    }

    if (grp == 0) {
        const float dv = dinv[node];
        short8 o;
#pragma unroll
        for (int j = 0; j < 8; j++) o[j] = (short)f2b(acc[j] * dv);
        *(short8*)&tb[node * 128 + fl * 8] = o;
    }
}

// ---------------- GEMM: out = [rowscale*] relu(t @ W + b), bf16 MFMA ----------------
__global__ __launch_bounds__(256) void gemm_mfma(const unsigned short* __restrict__ tb,
                                                 const unsigned short* __restrict__ wb,
                                                 const float* __restrict__ bias,
                                                 const float* __restrict__ rowscale,
                                                 unsigned short* __restrict__ hout, int n) {
    const int lane = threadIdx.x & 63;
    const int wave = threadIdx.x >> 6;
    const int r0 = blockIdx.x * 64 + wave * 16;
    const int m = lane & 15;
    const int quad = lane >> 4;
    const short* A = (const short*)tb;
    const short* B = (const short*)wb;

    float4v acc[8];
#pragma unroll
    for (int nt = 0; nt < 8; nt++) acc[nt] = (float4v){0.f, 0.f, 0.f, 0.f};

#pragma unroll
    for (int ki = 0; ki < 4; ki++) {
        short8 a = *(const short8*)&A[(r0 + m) * 128 + ki * 32 + quad * 8];
#pragma unroll
        for (int nt = 0; nt < 8; nt++) {
            short8 b = *(const short8*)&B[((ki * 8 + nt) * 64 + lane) * 8];
            acc[nt] = __builtin_amdgcn_mfma_f32_16x16x32_bf16(a, b, acc[nt], 0, 0, 0);
        }
    }

    float sc[4];
#pragma unroll
    for (int reg = 0; reg < 4; reg++) {
        int row = r0 + quad * 4 + reg;
        sc[reg] = (rowscale && row < n) ? rowscale[row] : 1.f;
    }

#pragma unroll
    for (int nt = 0; nt < 8; nt++) {
        int c = nt * 16 + m;
        float bv = bias[c];
#pragma unroll
        for (int reg = 0; reg < 4; reg++) {
            int row = r0 + quad * 4 + reg;
            if (row < n) {
                float v = fmaxf(acc[nt][reg] + bv, 0.f) * sc[reg];
                hout[row * 128 + c] = f2b(v);
            }
        }
    }
}

// ---------------- pooling (batch sorted), bf16 input ----------------
__global__ __launch_bounds__(128) void pool_kernel(const unsigned short* __restrict__ h, const int* __restrict__ batch,
                                                   float* emb, int* cnt, int n) {
    const int f = threadIdx.x;        // 0..127
    const int n0 = blockIdx.x * 64;
    const int n1 = min(n0 + 64, n);
    float s = 0.f;
    int cloc = 0;
    int curg = batch[n0];
    for (int nn = n0; nn < n1; nn++) {
        int g = batch[nn];
        if (g != curg) {
            atomicAdd(&emb[curg * HIDDEN + f], s);
            if (f == 0) atomicAdd(&cnt[curg], cloc);
            s = 0.f;
            cloc = 0;
            curg = g;
        }
        s += b2f(h[nn * HIDDEN + f]);
        cloc++;
    }
    atomicAdd(&emb[curg * HIDDEN + f], s);
    if (f == 0) atomicAdd(&cnt[curg], cloc);
}

// ---------------- finalize ----------------
__global__ __launch_bounds__(128) void finalize_kernel(const float* __restrict__ emb, const int* __restrict__ cnt,
                                                       const float* __restrict__ linW, const float* __restrict__ linb,
                                                       float* out) {
    const int g = blockIdx.x;
    const int f = threadIdx.x;
    __shared__ float es[128];
    float c = (float)max(cnt[g], 1);
    float e = emb[g * HIDDEN + f] / c;
    out[NUM_GRAPHS * NUM_CLASSES + g * HIDDEN + f] = e;
    es[f] = e;
    __syncthreads();
    if (f < NUM_CLASSES) {
        float s = linb[f];
        for (int k = 0; k < HIDDEN; k++) s += es[k] * linW[k * NUM_CLASSES + f];
        out[g * NUM_CLASSES + f] = s;
    }
}

extern "C" void kernel_launch(void* const* d_in, const int* in_sizes, int n_in,
                              void* d_out, int out_size, void* d_ws, size_t ws_size,
                              hipStream_t stream) {
    const float* x    = (const float*)d_in[0];
    const int*   ei   = (const int*)d_in[1];
    const int*   batch= (const int*)d_in[2];
    const float* W0   = (const float*)d_in[3];
    const float* b0   = (const float*)d_in[4];
    const float* W1   = (const float*)d_in[5];
    const float* b1   = (const float*)d_in[6];
    const float* W2   = (const float*)d_in[7];
    const float* b2   = (const float*)d_in[8];
    const float* linW = (const float*)d_in[9];
    const float* linb = (const float*)d_in[10];
    float* out = (float*)d_out;

    const int N = N_NODES;
    const int E = in_sizes[1] / 2;
    const int M = E + N;
    const int* srcp = ei;
    const int* dstp = ei + E;

    char* w = (char*)d_ws;
    size_t o = 0;
    auto alloc = [&](size_t bytes) { size_t r = o; o += (bytes + 255) & ~(size_t)255; return r; };
    int*            off_i   = (int*)           (w + alloc((size_t)(N + 1) * 4));
    int*            deg     = (int*)           (w + alloc((size_t)N * DEG_STRIDE * 4));
    float*          dinv    = (float*)         (w + alloc((size_t)N * 4));
    int*            partial = (int*)           (w + alloc((size_t)SCAN_NB * 4));
    int*            rank    = (int*)           (w + alloc((size_t)E * 4));
    int*            csr_col = (int*)           (w + alloc((size_t)M * 4));
    unsigned short* xs      = (unsigned short*)(w + alloc((size_t)N_PAD * HIDDEN * 2));
    unsigned short* tb      = (unsigned short*)(w + alloc((size_t)N_PAD * HIDDEN * 2));
    unsigned short* hb      = (unsigned short*)(w + alloc((size_t)N_PAD * HIDDEN * 2));
    unsigned short* wb      = (unsigned short*)(w + alloc((size_t)3 * 16384 * 2));
    float*          emb     = (float*)         (w + alloc((size_t)NUM_GRAPHS * HIDDEN * 4));
    int*            cnt     = (int*)           (w + alloc((size_t)NUM_GRAPHS * 4));

    hipMemsetAsync(deg, 0, (size_t)N * DEG_STRIDE * 4, stream);
    hipMemsetAsync(emb, 0, (size_t)(NUM_GRAPHS * HIDDEN * 4 + 256 + NUM_GRAPHS * 4), stream); // emb + pad + cnt

    const int edge_blocks = (E + 255) / 256;

    prologue<<<CONV_BLOCKS + edge_blocks, 256, 0, stream>>>(W0, W1, W2, wb, dstp, deg, rank, E);

    scan_b1<<<SCAN_NB, 256, 0, stream>>>(deg, partial, dinv, N);
    scan_b3<<<SCAN_NB, 256, 0, stream>>>(deg, partial, off_i, csr_col, N);

    midprep<<<CASTX_BLOCKS + edge_blocks, 256, 0, stream>>>(x, dinv, xs, srcp, dstp, rank, off_i, csr_col, E);

    const int gemm_grid = (N + 63) / 64;   // 782
    const int agg_grid  = (N + 3) / 4;     // 12500

    agg_bf16<<<agg_grid, 256, 0, stream>>>(xs, off_i, csr_col, dinv, tb, N);
    gemm_mfma<<<gemm_grid, 256, 0, stream>>>(tb, wb + 0 * 16384, b0, dinv, hb, N);
    agg_bf16<<<agg_grid, 256, 0, stream>>>(hb, off_i, csr_col, dinv, tb, N);
    gemm_mfma<<<gemm_grid, 256, 0, stream>>>(tb, wb + 1 * 16384, b1, dinv, hb, N);
    agg_bf16<<<agg_grid, 256, 0, stream>>>(hb, off_i, csr_col, dinv, tb, N);
    gemm_mfma<<<gemm_grid, 256, 0, stream>>>(tb, wb + 2 * 16384, b2, (const float*)nullptr, hb, N);

    pool_kernel<<<(N + 63) / 64, 128, 0, stream>>>(hb, batch, emb, cnt, N);
    finalize_kernel<<<NUM_GRAPHS, 128, 0, stream>>>(emb, cnt, linW, linb, out);
}